// Round 2
// baseline (366.040 us; speedup 1.0000x reference)
//
#include <hip/hip_runtime.h>

#define B_   1024
#define G_   512
#define K_   128
#define J_   129
#define E2_  128
#define KK_  16512      /* K_*J_ */
#define KKE_ 16640      /* KK_ + K_ (appended wimg columns) */
#define KKP_ 16896      /* padded: SPLITS*KCHUNK */
#define SPLITS 16
#define KCHUNK 1056     /* KKP_/SPLITS */
#define BK_  32
#define KSTEPS 33       /* KCHUNK/BK_ */
#define GS_  8          /* g-splits for table partials */

using short8 = __attribute__((ext_vector_type(8))) short;
using f32x4  = __attribute__((ext_vector_type(4))) float;

__device__ __forceinline__ float bf2f(unsigned short h){
  return __uint_as_float(((unsigned int)h) << 16);
}
__device__ __forceinline__ unsigned short f2bf(float f){
  unsigned int u = __float_as_uint(f);
  u += 0x7fffu + ((u >> 16) & 1u);          // round-to-nearest-even
  return (unsigned short)(u >> 16);
}

// ---- block (128-thread, 2-wave) reductions -------------------------------
__device__ __forceinline__ float blockSum128(float v, float* red, int t){
  #pragma unroll
  for (int off = 32; off > 0; off >>= 1) v += __shfl_down(v, off);
  __syncthreads();
  if ((t & 63) == 0) red[t >> 6] = v;
  __syncthreads();
  float r = red[0] + red[1];
  __syncthreads();
  return r;
}
__device__ __forceinline__ float blockMax128(float v, float* red, int t){
  #pragma unroll
  for (int off = 32; off > 0; off >>= 1) v = fmaxf(v, __shfl_down(v, off));
  __syncthreads();
  if ((t & 63) == 0) red[t >> 6] = v;
  __syncthreads();
  float r = fmaxf(red[0], red[1]);
  __syncthreads();
  return r;
}
__device__ __forceinline__ int blockArgmax128(float v, float* redf, int* redi, int t){
  int i = t;
  #pragma unroll
  for (int off = 32; off > 0; off >>= 1){
    float ov = __shfl_down(v, off);
    int   oi = __shfl_down(i, off);
    if (ov > v || (ov == v && oi < i)){ v = ov; i = oi; }
  }
  __syncthreads();
  if ((t & 63) == 0){ redf[t >> 6] = v; redi[t >> 6] = i; }
  __syncthreads();
  float v0 = redf[0], v1 = redf[1];
  int   i0 = redi[0], i1 = redi[1];
  int res = (v1 > v0 || (v1 == v0 && i1 < i0)) ? i1 : i0;
  __syncthreads();
  return res;
}

// ---- norms: c1norm[k]=sum_g wimg^2, w3norm[k]=sum_e wrec^2, w6norm[j]=sum_e wrec2^2
__global__ __launch_bounds__(128) void norms_kernel(
    const float* __restrict__ wimg, const float* __restrict__ wrec,
    const float* __restrict__ wrec2, float* __restrict__ c1norm,
    float* __restrict__ w3norm, float* __restrict__ w6norm){
  int t = threadIdx.x;
  if (blockIdx.x == 0){
    float s = 0.f;
    for (int g = 0; g < G_; g++){ float v = wimg[g*K_ + t]; s += v*v; }
    c1norm[t] = s;
  } else if (blockIdx.x == 1){
    float s = 0.f;
    for (int e = 0; e < E2_; e++){ float v = wrec[t*E2_ + e]; s += v*v; }
    w3norm[t] = s;
  } else {
    float s = 0.f;
    for (int e = 0; e < E2_; e++){ float v = wrec2[t*E2_ + e]; s += v*v; }
    w6norm[t] = s;
    if (t == 0){
      float s2 = 0.f;
      for (int e = 0; e < E2_; e++){ float v = wrec2[128*E2_ + e]; s2 += v*v; }
      w6norm[128] = s2;
    }
  }
}

// ---- tables partials over g: sqp[gs][n] = sum_g w2^2, crp = sum_g wimg*w2 (n = k*129+j)
__global__ __launch_bounds__(128) void tables_part_kernel(
    const float* __restrict__ wimg2, const float* __restrict__ wimg,
    float* __restrict__ sqp, float* __restrict__ crp){
  int n  = blockIdx.x * 128 + threadIdx.x;   // [0,16512)
  int gs = blockIdx.y;
  int k = n / J_;
  float s0=0,s1=0,s2=0,s3=0, c0=0,c1=0,c2=0,c3=0;
  int gbase = gs * (G_/GS_);
  #pragma unroll 2
  for (int g = gbase; g < gbase + G_/GS_; g += 4){
    float w0 = wimg2[(size_t)(g  )*KK_ + n];
    float w1 = wimg2[(size_t)(g+1)*KK_ + n];
    float w2 = wimg2[(size_t)(g+2)*KK_ + n];
    float w3 = wimg2[(size_t)(g+3)*KK_ + n];
    s0 += w0*w0; s1 += w1*w1; s2 += w2*w2; s3 += w3*w3;
    c0 += wimg[(g  )*K_ + k]*w0;
    c1 += wimg[(g+1)*K_ + k]*w1;
    c2 += wimg[(g+2)*K_ + k]*w2;
    c3 += wimg[(g+3)*K_ + k]*w3;
  }
  sqp[(size_t)gs*KK_ + n] = (s0+s1)+(s2+s3);
  crp[(size_t)gs*KK_ + n] = (c0+c1)+(c2+c3);
}
__global__ __launch_bounds__(128) void tables_reduce_kernel(
    const float* __restrict__ sqp, const float* __restrict__ crp,
    float* __restrict__ sq2, float* __restrict__ cross){
  int n = blockIdx.x * 128 + threadIdx.x;
  float s = 0.f, c = 0.f;
  #pragma unroll
  for (int gs = 0; gs < GS_; gs++){
    s += sqp[(size_t)gs*KK_ + n];
    c += crp[(size_t)gs*KK_ + n];
  }
  sq2[n] = s; cross[n] = c;
}

// ---- wimg2 (+ appended wimg cols + zero pad) -> bf16, layout [G][KKP_]
__global__ __launch_bounds__(256) void w2conv_kernel(
    const float* __restrict__ wimg2, const float* __restrict__ wimg,
    unsigned short* __restrict__ W2){
  int g = blockIdx.x;
  const float* src = wimg2 + (size_t)g * KK_;
  unsigned short* dst = W2 + (size_t)g * KKP_;
  for (int kk = threadIdx.x; kk < KKP_; kk += 256){
    float v;
    if (kk < KK_)       v = src[kk];
    else if (kk < KKE_) v = wimg[g*K_ + (kk - KK_)];
    else                v = 0.f;
    dst[kk] = f2bf(v);
  }
}

// ---- encode+decode probabilities per b; writes R row (bf16): R[b,kk]=p_k*q_j (+p tail)
__global__ __launch_bounds__(128) void encdec_kernel(
    const float* __restrict__ img,  const float* __restrict__ wimg,
    const float* __restrict__ wrec, const float* __restrict__ wrec2,
    const unsigned short* __restrict__ W2,
    const float* __restrict__ c1norm, const float* __restrict__ w3norm,
    const float* __restrict__ w6norm, const float* __restrict__ sq2,
    const float* __restrict__ cross, unsigned short* __restrict__ Rm){
  __shared__ float simg[G_];
  __shared__ float sw[J_*J_];        // padded code matrix (wrec then wrec2)
  __shared__ float sp[K_];           // xp1, then p (xp_d)
  __shared__ float sq[J_];           // xp2, then q (xp2_d)
  __shared__ float slat[E2_];
  __shared__ float redf[2];
  __shared__ int   redi[2];
  __shared__ float bc[2];

  int t = threadIdx.x;
  int b = blockIdx.x;

  // -- stage 1: xp1 = softmax_k( -(||img-c_k||^2)/512 )
  simg[t      ] = img[b*G_ + t      ];
  simg[t + 128] = img[b*G_ + t + 128];
  simg[t + 256] = img[b*G_ + t + 256];
  simg[t + 384] = img[b*G_ + t + 384];
  __syncthreads();
  float a0 = simg[t], a1 = simg[t+128], a2 = simg[t+256], a3 = simg[t+384];
  float imgnorm = blockSum128(a0*a0 + a1*a1 + a2*a2 + a3*a3, redf, t);

  float d10=0,d11=0,d12=0,d13=0;
  const float* wcol = wimg + t;
  for (int g = 0; g < G_; g += 4){
    d10 += simg[g  ] * wcol[(g  )*K_];
    d11 += simg[g+1] * wcol[(g+1)*K_];
    d12 += simg[g+2] * wcol[(g+2)*K_];
    d13 += simg[g+3] * wcol[(g+3)*K_];
  }
  float d1 = (d10+d11)+(d12+d13);
  float xh1 = -(imgnorm - 2.f*d1 + c1norm[t]) * (1.f/512.f);
  float m1 = blockMax128(xh1, redf, t);
  float ex1 = expf(xh1 - m1);
  float s1 = blockSum128(ex1, redf, t);
  sp[t] = ex1 / s1;
  __syncthreads();

  // -- stage 2+3: lat = xp1 @ wrec ; xh3 = -(||lat - wrec_k||^2)/128 ; p, idx
  for (int nn = t; nn < K_*E2_; nn += 128){
    int kk = nn >> 7, e = nn & 127;
    sw[kk*J_ + e] = wrec[nn];
  }
  __syncthreads();
  float lat = 0.f;
  #pragma unroll 8
  for (int k = 0; k < K_; k++) lat += sp[k] * sw[k*J_ + t];
  slat[t] = lat;
  float latnorm = blockSum128(lat*lat, redf, t);
  float d3 = 0.f;
  #pragma unroll 8
  for (int e = 0; e < E2_; e++) d3 += slat[e] * sw[t*J_ + e];
  float xh3 = -(latnorm - 2.f*d3 + w3norm[t]) * (1.f/128.f);
  float m3 = blockMax128(xh3, redf, t);
  float ex3 = expf(xh3 - m3);
  float s3 = blockSum128(ex3, redf, t);
  float p = ex3 / s3;
  int idxb = blockArgmax128(xh3, redf, redi, t);
  sp[t] = p;                        // overwrite xp1 with decode p
  if (t == idxb) bc[0] = d1;
  __syncthreads();
  float dsq = imgnorm - 2.f*bc[0] + c1norm[idxb];

  // -- stage 5: xh2[j] = -(dsq - 2*(dotimg - cross) + sq2)/512 ; xp2
  const unsigned short* Wcol = W2 + (size_t)idxb * J_;
  float di0=0,di1=0,di2=0,di3=0, dxa=0;
  for (int g = 0; g < G_; g += 4){
    const unsigned short* r0 = Wcol + (size_t)g*KKP_;
    di0 += simg[g  ] * bf2f(r0[0*KKP_ + t]);
    di1 += simg[g+1] * bf2f(r0[1*KKP_ + t]);
    di2 += simg[g+2] * bf2f(r0[2*KKP_ + t]);
    di3 += simg[g+3] * bf2f(r0[3*KKP_ + t]);
    if (t == 0){
      dxa += simg[g  ]*bf2f(r0[0*KKP_ + 128]) + simg[g+1]*bf2f(r0[1*KKP_ + 128])
           + simg[g+2]*bf2f(r0[2*KKP_ + 128]) + simg[g+3]*bf2f(r0[3*KKP_ + 128]);
    }
  }
  float di = (di0+di1)+(di2+di3);
  int nb = idxb*J_ + t;
  float xh2 = -(dsq - 2.f*(di - cross[nb]) + sq2[nb]) * (1.f/512.f);
  float xh2b = -3e38f;
  if (t == 0){
    int nb2 = idxb*J_ + 128;
    xh2b = -(dsq - 2.f*(dxa - cross[nb2]) + sq2[nb2]) * (1.f/512.f);
  }
  float m2 = blockMax128(fmaxf(xh2, xh2b), redf, t);
  float ea = expf(xh2 - m2);
  float eb = (t == 0) ? expf(xh2b - m2) : 0.f;
  float s2 = blockSum128(ea + eb, redf, t);
  sq[t] = ea / s2;
  if (t == 0) sq[128] = eb / s2;
  __syncthreads();

  // -- stage 6+7: lat2 = xp2 @ wrec2 ; q = softmax_j( -(||lat2-wrec2_j||^2)/128 )
  for (int nn = t; nn < J_*E2_; nn += 128){
    int j = nn >> 7, e = nn & 127;
    sw[j*J_ + e] = wrec2[nn];
  }
  __syncthreads();
  float lat2 = 0.f;
  #pragma unroll 8
  for (int j = 0; j < J_; j++) lat2 += sq[j] * sw[j*J_ + t];
  slat[t] = lat2;
  float l2n = blockSum128(lat2*lat2, redf, t);
  float d6 = 0.f, d6b = 0.f;
  #pragma unroll 8
  for (int e = 0; e < E2_; e++) d6 += slat[e] * sw[t*J_ + e];
  if (t == 0){
    for (int e = 0; e < E2_; e++) d6b += slat[e] * sw[128*J_ + e];
  }
  float xh6 = -(l2n - 2.f*d6 + w6norm[t]) * (1.f/128.f);
  float xh6b = -3e38f;
  if (t == 0) xh6b = -(l2n - 2.f*d6b + w6norm[128]) * (1.f/128.f);
  float m6 = blockMax128(fmaxf(xh6, xh6b), redf, t);
  float e6 = expf(xh6 - m6);
  float e6b = (t == 0) ? expf(xh6b - m6) : 0.f;
  float s6 = blockSum128(e6 + e6b, redf, t);
  sq[t] = e6 / s6;
  if (t == 0) sq[128] = e6b / s6;
  __syncthreads();

  // -- R fill: [0,KK_): p_k*q_j ; [KK_,KKE_): p ; rest 0
  unsigned short* Rrow = Rm + (size_t)b * KKP_;
  for (int kk = t; kk < KKP_; kk += 128){
    float v;
    if (kk < KK_){
      int k = kk / J_;
      int j = kk - k*J_;
      v = sp[k] * sq[j];
    } else if (kk < KKE_){
      v = sp[kk - KK_];
    } else v = 0.f;
    Rrow[kk] = f2bf(v);
  }
}

// ---- big einsum as bf16 NT GEMM with split-K:
// part[z][b][g] = sum_{kk in chunk z} R[b,kk]*W2[g,kk]
__global__ __launch_bounds__(256) void gemm_kernel(
    const unsigned short* __restrict__ Rm, const unsigned short* __restrict__ W2,
    float* __restrict__ part){
  __shared__ __align__(16) unsigned int lds[2*128*20];   // 80B-stride rows, A then B
  unsigned int* lA = lds;
  unsigned int* lB = lds + 128*20;
  int tid = threadIdx.x;
  int l = tid & 63;
  int w = tid >> 6;
  int wr = (w >> 1) * 64, wc = (w & 1) * 64;
  int b0 = blockIdx.y * 128, g0 = blockIdx.x * 128;
  size_t kkbase = (size_t)blockIdx.z * KCHUNK;

  // staging: 256 threads cover rows [0,64) x 4 chunks of 16B; second load row+64.
  int srow = tid >> 2, scol = tid & 3;
  const unsigned short* pa = Rm + (size_t)(b0 + srow)*KKP_ + kkbase + scol*8;
  const unsigned short* pb = W2 + (size_t)(g0 + srow)*KKP_ + kkbase + scol*8;
  const size_t half = (size_t)64 * KKP_;
  unsigned int woff = srow*20 + scol*4;

  int lrow = l & 15, lko = (l >> 4) << 2;

  f32x4 zero4 = {0.f, 0.f, 0.f, 0.f};
  f32x4 acc[4][4];
  #pragma unroll
  for (int mi = 0; mi < 4; mi++)
    #pragma unroll
    for (int ni = 0; ni < 4; ni++) acc[mi][ni] = zero4;

  for (int s = 0; s < KSTEPS; s++){
    uint4 va0 = *(const uint4*)pa;
    uint4 va1 = *(const uint4*)(pa + half);
    uint4 vb0 = *(const uint4*)pb;
    uint4 vb1 = *(const uint4*)(pb + half);
    pa += BK_; pb += BK_;
    __syncthreads();                       // previous tile fully consumed
    *(uint4*)(lA + woff)          = va0;
    *(uint4*)(lA + woff + 64*20)  = va1;
    *(uint4*)(lB + woff)          = vb0;
    *(uint4*)(lB + woff + 64*20)  = vb1;
    __syncthreads();
    short8 af[4], bfv[4];
    #pragma unroll
    for (int mi = 0; mi < 4; mi++)
      af[mi] = *(const short8*)(lA + (wr + mi*16 + lrow)*20 + lko);
    #pragma unroll
    for (int ni = 0; ni < 4; ni++)
      bfv[ni] = *(const short8*)(lB + (wc + ni*16 + lrow)*20 + lko);
    #pragma unroll
    for (int mi = 0; mi < 4; mi++)
      #pragma unroll
      for (int ni = 0; ni < 4; ni++)
        acc[mi][ni] = __builtin_amdgcn_mfma_f32_16x16x32_bf16(af[mi], bfv[ni], acc[mi][ni], 0, 0, 0);
  }

  float* P = part + ((size_t)blockIdx.z * B_ + b0) * G_ + g0;
  int rh = (l >> 4) << 2, cl = l & 15;
  #pragma unroll
  for (int mi = 0; mi < 4; mi++)
    #pragma unroll
    for (int ni = 0; ni < 4; ni++)
      #pragma unroll
      for (int r = 0; r < 4; r++){
        int row = wr + mi*16 + rh + r;
        int col = wc + ni*16 + cl;
        P[(size_t)row*G_ + col] = acc[mi][ni][r];
      }
}

// ---- loss[b] = mean_g ( (sum_z part[z][b][g]) - img[b][g] )^2
__global__ __launch_bounds__(128) void loss_kernel(
    const float* __restrict__ img, const float* __restrict__ part,
    float* __restrict__ out){
  __shared__ float redf[2];
  int t = threadIdx.x, b = blockIdx.x;
  float acc = 0.f;
  for (int g = t; g < G_; g += 128){
    float x = 0.f;
    #pragma unroll
    for (int z = 0; z < SPLITS; z++)
      x += part[((size_t)z*B_ + b)*G_ + g];
    float d = x - img[b*G_ + g];
    acc += d*d;
  }
  float s = blockSum128(acc, redf, t);
  if (t == 0) out[b] = s * (1.f/512.f);
}

extern "C" void kernel_launch(void* const* d_in, const int* in_sizes, int n_in,
                              void* d_out, int out_size, void* d_ws, size_t ws_size,
                              hipStream_t stream){
  (void)in_sizes; (void)n_in; (void)out_size; (void)ws_size;
  const float* img   = (const float*)d_in[0];
  const float* wimg  = (const float*)d_in[1];
  const float* wrec  = (const float*)d_in[2];
  const float* wrec2 = (const float*)d_in[3];
  const float* wimg2 = (const float*)d_in[4];
  float* out = (float*)d_out;

  char* ws = (char*)d_ws;
  size_t off = 0;
  auto alloc = [&](size_t bytes) -> void* {
    void* p = ws + off;
    off += (bytes + 255) & ~(size_t)255;
    return p;
  };
  unsigned short* W2   = (unsigned short*)alloc((size_t)G_ * KKP_ * 2);
  unsigned short* Rm   = (unsigned short*)alloc((size_t)B_ * KKP_ * 2);
  float* part   = (float*)alloc((size_t)SPLITS * B_ * G_ * 4);
  float* sqp    = (float*)alloc((size_t)GS_ * KK_ * 4);
  float* crp    = (float*)alloc((size_t)GS_ * KK_ * 4);
  float* sq2    = (float*)alloc((size_t)KK_ * 4);
  float* cross  = (float*)alloc((size_t)KK_ * 4);
  float* c1norm = (float*)alloc(K_ * 4);
  float* w3norm = (float*)alloc(K_ * 4);
  float* w6norm = (float*)alloc(J_ * 4);

  norms_kernel<<<dim3(3), dim3(128), 0, stream>>>(wimg, wrec, wrec2, c1norm, w3norm, w6norm);
  tables_part_kernel<<<dim3(129, GS_), dim3(128), 0, stream>>>(wimg2, wimg, sqp, crp);
  tables_reduce_kernel<<<dim3(129), dim3(128), 0, stream>>>(sqp, crp, sq2, cross);
  w2conv_kernel<<<dim3(512), dim3(256), 0, stream>>>(wimg2, wimg, W2);
  encdec_kernel<<<dim3(1024), dim3(128), 0, stream>>>(img, wimg, wrec, wrec2, W2,
      c1norm, w3norm, w6norm, sq2, cross, Rm);
  gemm_kernel<<<dim3(4, 8, SPLITS), dim3(256), 0, stream>>>(Rm, W2, part);
  loss_kernel<<<dim3(1024), dim3(128), 0, stream>>>(img, part, out);
}

// Round 3
// 242.642 us; speedup vs baseline: 1.5086x; 1.5086x over previous
//
#include <hip/hip_runtime.h>

#define B_   1024
#define G_   512
#define K_   128
#define J_   129
#define E2_  128
#define KK_  16512      /* K_*J_ */
#define KKE_ 16640      /* KK_ + K_ (appended wimg columns) */
#define KKP_ 16896      /* padded: SPLITS*KCHUNK */
#define SPLITS 16
#define KCHUNK 1056     /* KKP_/SPLITS */
#define BK_  32
#define KSTEPS 33       /* KCHUNK/BK_ */
#define GS_  8          /* g-splits for table partials */

using short8 = __attribute__((ext_vector_type(8))) short;
using f32x4  = __attribute__((ext_vector_type(4))) float;

__device__ __forceinline__ float bf2f(unsigned short h){
  return __uint_as_float(((unsigned int)h) << 16);
}
__device__ __forceinline__ unsigned short f2bf(float f){
  unsigned int u = __float_as_uint(f);
  u += 0x7fffu + ((u >> 16) & 1u);          // round-to-nearest-even
  return (unsigned short)(u >> 16);
}

// ---- block (128-thread, 2-wave) reductions -------------------------------
__device__ __forceinline__ float blockSum128(float v, float* red, int t){
  #pragma unroll
  for (int off = 32; off > 0; off >>= 1) v += __shfl_down(v, off);
  __syncthreads();
  if ((t & 63) == 0) red[t >> 6] = v;
  __syncthreads();
  float r = red[0] + red[1];
  __syncthreads();
  return r;
}
__device__ __forceinline__ float blockMax128(float v, float* red, int t){
  #pragma unroll
  for (int off = 32; off > 0; off >>= 1) v = fmaxf(v, __shfl_down(v, off));
  __syncthreads();
  if ((t & 63) == 0) red[t >> 6] = v;
  __syncthreads();
  float r = fmaxf(red[0], red[1]);
  __syncthreads();
  return r;
}
__device__ __forceinline__ int blockArgmax128(float v, float* redf, int* redi, int t){
  int i = t;
  #pragma unroll
  for (int off = 32; off > 0; off >>= 1){
    float ov = __shfl_down(v, off);
    int   oi = __shfl_down(i, off);
    if (ov > v || (ov == v && oi < i)){ v = ov; i = oi; }
  }
  __syncthreads();
  if ((t & 63) == 0){ redf[t >> 6] = v; redi[t >> 6] = i; }
  __syncthreads();
  float v0 = redf[0], v1 = redf[1];
  int   i0 = redi[0], i1 = redi[1];
  int res = (v1 > v0 || (v1 == v0 && i1 < i0)) ? i1 : i0;
  __syncthreads();
  return res;
}

// ---- norms: c1norm[k]=sum_g wimg^2, w3norm[k]=sum_e wrec^2, w6norm[j]=sum_e wrec2^2
// Parallelized: 1024 threads/block, coalesced loads, wave-shuffle reductions.
__global__ __launch_bounds__(1024) void norms_kernel(
    const float* __restrict__ wimg, const float* __restrict__ wrec,
    const float* __restrict__ wrec2, float* __restrict__ c1norm,
    float* __restrict__ w3norm, float* __restrict__ w6norm){
  int t = threadIdx.x;
  if (blockIdx.x == 0){
    // 8 g-slices x 128 k-lanes; consecutive t -> consecutive k (coalesced)
    __shared__ float red[8][128];
    int k = t & 127, sl = t >> 7;
    float s = 0.f;
    int g0 = sl * (G_/8);
    for (int g = g0; g < g0 + G_/8; g++){
      float v = wimg[g*K_ + k]; s += v*v;
    }
    red[sl][k] = s;
    __syncthreads();
    if (t < 128){
      float r = 0.f;
      #pragma unroll
      for (int i = 0; i < 8; i++) r += red[i][t];
      c1norm[t] = r;
    }
  } else if (blockIdx.x == 1){
    // one wave per row k, lanes cover e (two coalesced 64-lane chunks)
    int wave = t >> 6, lane = t & 63;
    for (int k = wave; k < K_; k += 16){
      float v0 = wrec[k*E2_ + lane], v1 = wrec[k*E2_ + 64 + lane];
      float s = v0*v0 + v1*v1;
      #pragma unroll
      for (int off = 32; off > 0; off >>= 1) s += __shfl_down(s, off);
      if (lane == 0) w3norm[k] = s;
    }
  } else {
    int wave = t >> 6, lane = t & 63;
    for (int j = wave; j < J_; j += 16){
      float v0 = wrec2[j*E2_ + lane], v1 = wrec2[j*E2_ + 64 + lane];
      float s = v0*v0 + v1*v1;
      #pragma unroll
      for (int off = 32; off > 0; off >>= 1) s += __shfl_down(s, off);
      if (lane == 0) w6norm[j] = s;
    }
  }
}

// ---- tables partials over g: sqp[gs][n] = sum_g w2^2, crp = sum_g wimg*w2 (n = k*129+j)
__global__ __launch_bounds__(128) void tables_part_kernel(
    const float* __restrict__ wimg2, const float* __restrict__ wimg,
    float* __restrict__ sqp, float* __restrict__ crp){
  int n  = blockIdx.x * 128 + threadIdx.x;   // [0,16512)
  int gs = blockIdx.y;
  int k = n / J_;
  float s0=0,s1=0,s2=0,s3=0, c0=0,c1=0,c2=0,c3=0;
  int gbase = gs * (G_/GS_);
  #pragma unroll 2
  for (int g = gbase; g < gbase + G_/GS_; g += 4){
    float w0 = wimg2[(size_t)(g  )*KK_ + n];
    float w1 = wimg2[(size_t)(g+1)*KK_ + n];
    float w2 = wimg2[(size_t)(g+2)*KK_ + n];
    float w3 = wimg2[(size_t)(g+3)*KK_ + n];
    s0 += w0*w0; s1 += w1*w1; s2 += w2*w2; s3 += w3*w3;
    c0 += wimg[(g  )*K_ + k]*w0;
    c1 += wimg[(g+1)*K_ + k]*w1;
    c2 += wimg[(g+2)*K_ + k]*w2;
    c3 += wimg[(g+3)*K_ + k]*w3;
  }
  sqp[(size_t)gs*KK_ + n] = (s0+s1)+(s2+s3);
  crp[(size_t)gs*KK_ + n] = (c0+c1)+(c2+c3);
}
__global__ __launch_bounds__(128) void tables_reduce_kernel(
    const float* __restrict__ sqp, const float* __restrict__ crp,
    float* __restrict__ sq2, float* __restrict__ cross){
  int n = blockIdx.x * 128 + threadIdx.x;
  float s = 0.f, c = 0.f;
  #pragma unroll
  for (int gs = 0; gs < GS_; gs++){
    s += sqp[(size_t)gs*KK_ + n];
    c += crp[(size_t)gs*KK_ + n];
  }
  sq2[n] = s; cross[n] = c;
}

// ---- wimg2 (+ appended wimg cols + zero pad) -> bf16, layout [G][KKP_]
__global__ __launch_bounds__(256) void w2conv_kernel(
    const float* __restrict__ wimg2, const float* __restrict__ wimg,
    unsigned short* __restrict__ W2){
  int g = blockIdx.x;
  const float* src = wimg2 + (size_t)g * KK_;
  unsigned short* dst = W2 + (size_t)g * KKP_;
  for (int kk = threadIdx.x; kk < KKP_; kk += 256){
    float v;
    if (kk < KK_)       v = src[kk];
    else if (kk < KKE_) v = wimg[g*K_ + (kk - KK_)];
    else                v = 0.f;
    dst[kk] = f2bf(v);
  }
}

// ---- encode+decode probabilities per b; writes R row (bf16): R[b,kk]=p_k*q_j (+p tail)
__global__ __launch_bounds__(128) void encdec_kernel(
    const float* __restrict__ img,  const float* __restrict__ wimg,
    const float* __restrict__ wrec, const float* __restrict__ wrec2,
    const unsigned short* __restrict__ W2,
    const float* __restrict__ c1norm, const float* __restrict__ w3norm,
    const float* __restrict__ w6norm, const float* __restrict__ sq2,
    const float* __restrict__ cross, unsigned short* __restrict__ Rm){
  __shared__ float simg[G_];
  __shared__ float sw[J_*J_];        // padded code matrix (wrec then wrec2)
  __shared__ float sp[K_];           // xp1, then p (xp_d)
  __shared__ float sq[J_];           // xp2, then q (xp2_d)
  __shared__ float slat[E2_];
  __shared__ float redf[2];
  __shared__ int   redi[2];
  __shared__ float bc[2];

  int t = threadIdx.x;
  int b = blockIdx.x;

  // -- stage 1: xp1 = softmax_k( -(||img-c_k||^2)/512 )
  simg[t      ] = img[b*G_ + t      ];
  simg[t + 128] = img[b*G_ + t + 128];
  simg[t + 256] = img[b*G_ + t + 256];
  simg[t + 384] = img[b*G_ + t + 384];
  __syncthreads();
  float a0 = simg[t], a1 = simg[t+128], a2 = simg[t+256], a3 = simg[t+384];
  float imgnorm = blockSum128(a0*a0 + a1*a1 + a2*a2 + a3*a3, redf, t);

  float d10=0,d11=0,d12=0,d13=0;
  const float* wcol = wimg + t;
  for (int g = 0; g < G_; g += 4){
    d10 += simg[g  ] * wcol[(g  )*K_];
    d11 += simg[g+1] * wcol[(g+1)*K_];
    d12 += simg[g+2] * wcol[(g+2)*K_];
    d13 += simg[g+3] * wcol[(g+3)*K_];
  }
  float d1 = (d10+d11)+(d12+d13);
  float xh1 = -(imgnorm - 2.f*d1 + c1norm[t]) * (1.f/512.f);
  float m1 = blockMax128(xh1, redf, t);
  float ex1 = expf(xh1 - m1);
  float s1 = blockSum128(ex1, redf, t);
  sp[t] = ex1 / s1;
  __syncthreads();

  // -- stage 2+3: lat = xp1 @ wrec ; xh3 = -(||lat - wrec_k||^2)/128 ; p, idx
  for (int nn = t; nn < K_*E2_; nn += 128){
    int kk = nn >> 7, e = nn & 127;
    sw[kk*J_ + e] = wrec[nn];
  }
  __syncthreads();
  float lat = 0.f;
  #pragma unroll 8
  for (int k = 0; k < K_; k++) lat += sp[k] * sw[k*J_ + t];
  slat[t] = lat;
  float latnorm = blockSum128(lat*lat, redf, t);
  float d3 = 0.f;
  #pragma unroll 8
  for (int e = 0; e < E2_; e++) d3 += slat[e] * sw[t*J_ + e];
  float xh3 = -(latnorm - 2.f*d3 + w3norm[t]) * (1.f/128.f);
  float m3 = blockMax128(xh3, redf, t);
  float ex3 = expf(xh3 - m3);
  float s3 = blockSum128(ex3, redf, t);
  float p = ex3 / s3;
  int idxb = blockArgmax128(xh3, redf, redi, t);
  sp[t] = p;                        // overwrite xp1 with decode p
  if (t == idxb) bc[0] = d1;
  __syncthreads();
  float dsq = imgnorm - 2.f*bc[0] + c1norm[idxb];

  // -- stage 5: xh2[j] = -(dsq - 2*(dotimg - cross) + sq2)/512 ; xp2
  const unsigned short* Wcol = W2 + (size_t)idxb * J_;
  float di0=0,di1=0,di2=0,di3=0, dxa=0;
  for (int g = 0; g < G_; g += 4){
    const unsigned short* r0 = Wcol + (size_t)g*KKP_;
    di0 += simg[g  ] * bf2f(r0[0*KKP_ + t]);
    di1 += simg[g+1] * bf2f(r0[1*KKP_ + t]);
    di2 += simg[g+2] * bf2f(r0[2*KKP_ + t]);
    di3 += simg[g+3] * bf2f(r0[3*KKP_ + t]);
    if (t == 0){
      dxa += simg[g  ]*bf2f(r0[0*KKP_ + 128]) + simg[g+1]*bf2f(r0[1*KKP_ + 128])
           + simg[g+2]*bf2f(r0[2*KKP_ + 128]) + simg[g+3]*bf2f(r0[3*KKP_ + 128]);
    }
  }
  float di = (di0+di1)+(di2+di3);
  int nb = idxb*J_ + t;
  float xh2 = -(dsq - 2.f*(di - cross[nb]) + sq2[nb]) * (1.f/512.f);
  float xh2b = -3e38f;
  if (t == 0){
    int nb2 = idxb*J_ + 128;
    xh2b = -(dsq - 2.f*(dxa - cross[nb2]) + sq2[nb2]) * (1.f/512.f);
  }
  float m2 = blockMax128(fmaxf(xh2, xh2b), redf, t);
  float ea = expf(xh2 - m2);
  float eb = (t == 0) ? expf(xh2b - m2) : 0.f;
  float s2 = blockSum128(ea + eb, redf, t);
  sq[t] = ea / s2;
  if (t == 0) sq[128] = eb / s2;
  __syncthreads();

  // -- stage 6+7: lat2 = xp2 @ wrec2 ; q = softmax_j( -(||lat2-wrec2_j||^2)/128 )
  for (int nn = t; nn < J_*E2_; nn += 128){
    int j = nn >> 7, e = nn & 127;
    sw[j*J_ + e] = wrec2[nn];
  }
  __syncthreads();
  float lat2 = 0.f;
  #pragma unroll 8
  for (int j = 0; j < J_; j++) lat2 += sq[j] * sw[j*J_ + t];
  slat[t] = lat2;
  float l2n = blockSum128(lat2*lat2, redf, t);
  float d6 = 0.f, d6b = 0.f;
  #pragma unroll 8
  for (int e = 0; e < E2_; e++) d6 += slat[e] * sw[t*J_ + e];
  if (t == 0){
    for (int e = 0; e < E2_; e++) d6b += slat[e] * sw[128*J_ + e];
  }
  float xh6 = -(l2n - 2.f*d6 + w6norm[t]) * (1.f/128.f);
  float xh6b = -3e38f;
  if (t == 0) xh6b = -(l2n - 2.f*d6b + w6norm[128]) * (1.f/128.f);
  float m6 = blockMax128(fmaxf(xh6, xh6b), redf, t);
  float e6 = expf(xh6 - m6);
  float e6b = (t == 0) ? expf(xh6b - m6) : 0.f;
  float s6 = blockSum128(e6 + e6b, redf, t);
  sq[t] = e6 / s6;
  if (t == 0) sq[128] = e6b / s6;
  __syncthreads();

  // -- R fill: [0,KK_): p_k*q_j ; [KK_,KKE_): p ; rest 0
  unsigned short* Rrow = Rm + (size_t)b * KKP_;
  for (int kk = t; kk < KKP_; kk += 128){
    float v;
    if (kk < KK_){
      int k = kk / J_;
      int j = kk - k*J_;
      v = sp[k] * sq[j];
    } else if (kk < KKE_){
      v = sp[kk - KK_];
    } else v = 0.f;
    Rrow[kk] = f2bf(v);
  }
}

// ---- big einsum as bf16 NT GEMM with split-K:
// part[z][b][g] = sum_{kk in chunk z} R[b,kk]*W2[g,kk]
__global__ __launch_bounds__(256) void gemm_kernel(
    const unsigned short* __restrict__ Rm, const unsigned short* __restrict__ W2,
    float* __restrict__ part){
  __shared__ __align__(16) unsigned int lds[2*128*20];   // 80B-stride rows, A then B
  unsigned int* lA = lds;
  unsigned int* lB = lds + 128*20;
  int tid = threadIdx.x;
  int l = tid & 63;
  int w = tid >> 6;
  int wr = (w >> 1) * 64, wc = (w & 1) * 64;
  int b0 = blockIdx.y * 128, g0 = blockIdx.x * 128;
  size_t kkbase = (size_t)blockIdx.z * KCHUNK;

  // staging: 256 threads cover rows [0,64) x 4 chunks of 16B; second load row+64.
  int srow = tid >> 2, scol = tid & 3;
  const unsigned short* pa = Rm + (size_t)(b0 + srow)*KKP_ + kkbase + scol*8;
  const unsigned short* pb = W2 + (size_t)(g0 + srow)*KKP_ + kkbase + scol*8;
  const size_t half = (size_t)64 * KKP_;
  unsigned int woff = srow*20 + scol*4;

  int lrow = l & 15, lko = (l >> 4) << 2;

  f32x4 zero4 = {0.f, 0.f, 0.f, 0.f};
  f32x4 acc[4][4];
  #pragma unroll
  for (int mi = 0; mi < 4; mi++)
    #pragma unroll
    for (int ni = 0; ni < 4; ni++) acc[mi][ni] = zero4;

  for (int s = 0; s < KSTEPS; s++){
    uint4 va0 = *(const uint4*)pa;
    uint4 va1 = *(const uint4*)(pa + half);
    uint4 vb0 = *(const uint4*)pb;
    uint4 vb1 = *(const uint4*)(pb + half);
    pa += BK_; pb += BK_;
    __syncthreads();                       // previous tile fully consumed
    *(uint4*)(lA + woff)          = va0;
    *(uint4*)(lA + woff + 64*20)  = va1;
    *(uint4*)(lB + woff)          = vb0;
    *(uint4*)(lB + woff + 64*20)  = vb1;
    __syncthreads();
    short8 af[4], bfv[4];
    #pragma unroll
    for (int mi = 0; mi < 4; mi++)
      af[mi] = *(const short8*)(lA + (wr + mi*16 + lrow)*20 + lko);
    #pragma unroll
    for (int ni = 0; ni < 4; ni++)
      bfv[ni] = *(const short8*)(lB + (wc + ni*16 + lrow)*20 + lko);
    #pragma unroll
    for (int mi = 0; mi < 4; mi++)
      #pragma unroll
      for (int ni = 0; ni < 4; ni++)
        acc[mi][ni] = __builtin_amdgcn_mfma_f32_16x16x32_bf16(af[mi], bfv[ni], acc[mi][ni], 0, 0, 0);
  }

  float* P = part + ((size_t)blockIdx.z * B_ + b0) * G_ + g0;
  int rh = (l >> 4) << 2, cl = l & 15;
  #pragma unroll
  for (int mi = 0; mi < 4; mi++)
    #pragma unroll
    for (int ni = 0; ni < 4; ni++)
      #pragma unroll
      for (int r = 0; r < 4; r++){
        int row = wr + mi*16 + rh + r;
        int col = wc + ni*16 + cl;
        P[(size_t)row*G_ + col] = acc[mi][ni][r];
      }
}

// ---- loss[b] = mean_g ( (sum_z part[z][b][g]) - img[b][g] )^2
__global__ __launch_bounds__(128) void loss_kernel(
    const float* __restrict__ img, const float* __restrict__ part,
    float* __restrict__ out){
  __shared__ float redf[2];
  int t = threadIdx.x, b = blockIdx.x;
  float acc = 0.f;
  for (int g = t; g < G_; g += 128){
    float x = 0.f;
    #pragma unroll
    for (int z = 0; z < SPLITS; z++)
      x += part[((size_t)z*B_ + b)*G_ + g];
    float d = x - img[b*G_ + g];
    acc += d*d;
  }
  float s = blockSum128(acc, redf, t);
  if (t == 0) out[b] = s * (1.f/512.f);
}

extern "C" void kernel_launch(void* const* d_in, const int* in_sizes, int n_in,
                              void* d_out, int out_size, void* d_ws, size_t ws_size,
                              hipStream_t stream){
  (void)in_sizes; (void)n_in; (void)out_size; (void)ws_size;
  const float* img   = (const float*)d_in[0];
  const float* wimg  = (const float*)d_in[1];
  const float* wrec  = (const float*)d_in[2];
  const float* wrec2 = (const float*)d_in[3];
  const float* wimg2 = (const float*)d_in[4];
  float* out = (float*)d_out;

  char* ws = (char*)d_ws;
  size_t off = 0;
  auto alloc = [&](size_t bytes) -> void* {
    void* p = ws + off;
    off += (bytes + 255) & ~(size_t)255;
    return p;
  };
  unsigned short* W2   = (unsigned short*)alloc((size_t)G_ * KKP_ * 2);
  unsigned short* Rm   = (unsigned short*)alloc((size_t)B_ * KKP_ * 2);
  float* part   = (float*)alloc((size_t)SPLITS * B_ * G_ * 4);
  float* sqp    = (float*)alloc((size_t)GS_ * KK_ * 4);
  float* crp    = (float*)alloc((size_t)GS_ * KK_ * 4);
  float* sq2    = (float*)alloc((size_t)KK_ * 4);
  float* cross  = (float*)alloc((size_t)KK_ * 4);
  float* c1norm = (float*)alloc(K_ * 4);
  float* w3norm = (float*)alloc(K_ * 4);
  float* w6norm = (float*)alloc(J_ * 4);

  norms_kernel<<<dim3(3), dim3(1024), 0, stream>>>(wimg, wrec, wrec2, c1norm, w3norm, w6norm);
  tables_part_kernel<<<dim3(129, GS_), dim3(128), 0, stream>>>(wimg2, wimg, sqp, crp);
  tables_reduce_kernel<<<dim3(129), dim3(128), 0, stream>>>(sqp, crp, sq2, cross);
  w2conv_kernel<<<dim3(512), dim3(256), 0, stream>>>(wimg2, wimg, W2);
  encdec_kernel<<<dim3(1024), dim3(128), 0, stream>>>(img, wimg, wrec, wrec2, W2,
      c1norm, w3norm, w6norm, sq2, cross, Rm);
  gemm_kernel<<<dim3(4, 8, SPLITS), dim3(256), 0, stream>>>(Rm, W2, part);
  loss_kernel<<<dim3(1024), dim3(128), 0, stream>>>(img, part, out);
}

// Round 4
// 157.337 us; speedup vs baseline: 2.3265x; 1.5422x over previous
//
#include <hip/hip_runtime.h>

#define B_   1024
#define G_   512
#define K_   128
#define J_   129
#define E2_  128
#define KK_  16512      /* K_*J_ */
#define KKE_ 16640      /* KK_ + K_ (appended wimg columns) */
#define KKP_ 16896      /* padded: SPLITS*KCHUNK */
#define SPLITS 16
#define KCHUNK 1056     /* KKP_/SPLITS */
#define BK_  32
#define KSTEPS 33       /* KCHUNK/BK_ */
#define GS_  8          /* g-splits for table partials */

using short8 = __attribute__((ext_vector_type(8))) short;
using f32x4  = __attribute__((ext_vector_type(4))) float;

__device__ __forceinline__ float bf2f(unsigned short h){
  return __uint_as_float(((unsigned int)h) << 16);
}
__device__ __forceinline__ unsigned short f2bf(float f){
  unsigned int u = __float_as_uint(f);
  u += 0x7fffu + ((u >> 16) & 1u);          // round-to-nearest-even
  return (unsigned short)(u >> 16);
}

// ---- block (256-thread, 4-wave) reductions -------------------------------
__device__ __forceinline__ float blockSum256(float v, float* red, int t){
  #pragma unroll
  for (int off = 32; off > 0; off >>= 1) v += __shfl_down(v, off);
  __syncthreads();
  if ((t & 63) == 0) red[t >> 6] = v;
  __syncthreads();
  float r = (red[0] + red[1]) + (red[2] + red[3]);
  __syncthreads();
  return r;
}
__device__ __forceinline__ float blockMax256(float v, float* red, int t){
  #pragma unroll
  for (int off = 32; off > 0; off >>= 1) v = fmaxf(v, __shfl_down(v, off));
  __syncthreads();
  if ((t & 63) == 0) red[t >> 6] = v;
  __syncthreads();
  float r = fmaxf(fmaxf(red[0], red[1]), fmaxf(red[2], red[3]));
  __syncthreads();
  return r;
}
__device__ __forceinline__ int blockArgmax256(float v, int i, float* redf, int* redi, int t){
  #pragma unroll
  for (int off = 32; off > 0; off >>= 1){
    float ov = __shfl_down(v, off);
    int   oi = __shfl_down(i, off);
    if (ov > v || (ov == v && oi < i)){ v = ov; i = oi; }
  }
  __syncthreads();
  if ((t & 63) == 0){ redf[t >> 6] = v; redi[t >> 6] = i; }
  __syncthreads();
  float bv = redf[0]; int bi = redi[0];
  #pragma unroll
  for (int wv = 1; wv < 4; wv++){
    float ov = redf[wv]; int oi = redi[wv];
    if (ov > bv || (ov == bv && oi < bi)){ bv = ov; bi = oi; }
  }
  __syncthreads();
  return bi;
}

// ---- norms + transposes (5 blocks x 1024 threads)
__global__ __launch_bounds__(1024) void norms_kernel(
    const float* __restrict__ wimg, const float* __restrict__ wrec,
    const float* __restrict__ wrec2, float* __restrict__ c1norm,
    float* __restrict__ w3norm, float* __restrict__ w6norm,
    float* __restrict__ wrecT, float* __restrict__ wrec2T){
  int t = threadIdx.x;
  if (blockIdx.x == 0){
    __shared__ float red[8][128];
    int k = t & 127, sl = t >> 7;
    float s = 0.f;
    int g0 = sl * (G_/8);
    for (int g = g0; g < g0 + G_/8; g++){
      float v = wimg[g*K_ + k]; s += v*v;
    }
    red[sl][k] = s;
    __syncthreads();
    if (t < 128){
      float r = 0.f;
      #pragma unroll
      for (int i = 0; i < 8; i++) r += red[i][t];
      c1norm[t] = r;
    }
  } else if (blockIdx.x == 1){
    int wave = t >> 6, lane = t & 63;
    for (int k = wave; k < K_; k += 16){
      float v0 = wrec[k*E2_ + lane], v1 = wrec[k*E2_ + 64 + lane];
      float s = v0*v0 + v1*v1;
      #pragma unroll
      for (int off = 32; off > 0; off >>= 1) s += __shfl_down(s, off);
      if (lane == 0) w3norm[k] = s;
    }
  } else if (blockIdx.x == 2){
    int wave = t >> 6, lane = t & 63;
    for (int j = wave; j < J_; j += 16){
      float v0 = wrec2[j*E2_ + lane], v1 = wrec2[j*E2_ + 64 + lane];
      float s = v0*v0 + v1*v1;
      #pragma unroll
      for (int off = 32; off > 0; off >>= 1) s += __shfl_down(s, off);
      if (lane == 0) w6norm[j] = s;
    }
  } else if (blockIdx.x == 3){
    for (int n = t; n < K_*E2_; n += 1024){
      int k = n >> 7, e = n & 127;
      wrecT[e*K_ + k] = wrec[n];
    }
  } else {
    for (int n = t; n < J_*E2_; n += 1024){
      int j = n >> 7, e = n & 127;
      wrec2T[e*J_ + j] = wrec2[n];
    }
  }
}

// ---- tables partials over g: sqp[gs][n] = sum_g w2^2, crp = sum_g wimg*w2 (n = k*129+j)
__global__ __launch_bounds__(128) void tables_part_kernel(
    const float* __restrict__ wimg2, const float* __restrict__ wimg,
    float* __restrict__ sqp, float* __restrict__ crp){
  int n  = blockIdx.x * 128 + threadIdx.x;   // [0,16512)
  int gs = blockIdx.y;
  int k = n / J_;
  float s0=0,s1=0,s2=0,s3=0, c0=0,c1=0,c2=0,c3=0;
  int gbase = gs * (G_/GS_);
  #pragma unroll 2
  for (int g = gbase; g < gbase + G_/GS_; g += 4){
    float w0 = wimg2[(size_t)(g  )*KK_ + n];
    float w1 = wimg2[(size_t)(g+1)*KK_ + n];
    float w2 = wimg2[(size_t)(g+2)*KK_ + n];
    float w3 = wimg2[(size_t)(g+3)*KK_ + n];
    s0 += w0*w0; s1 += w1*w1; s2 += w2*w2; s3 += w3*w3;
    c0 += wimg[(g  )*K_ + k]*w0;
    c1 += wimg[(g+1)*K_ + k]*w1;
    c2 += wimg[(g+2)*K_ + k]*w2;
    c3 += wimg[(g+3)*K_ + k]*w3;
  }
  sqp[(size_t)gs*KK_ + n] = (s0+s1)+(s2+s3);
  crp[(size_t)gs*KK_ + n] = (c0+c1)+(c2+c3);
}
__global__ __launch_bounds__(128) void tables_reduce_kernel(
    const float* __restrict__ sqp, const float* __restrict__ crp,
    float* __restrict__ sq2, float* __restrict__ cross){
  int n = blockIdx.x * 128 + threadIdx.x;
  float s = 0.f, c = 0.f;
  #pragma unroll
  for (int gs = 0; gs < GS_; gs++){
    s += sqp[(size_t)gs*KK_ + n];
    c += crp[(size_t)gs*KK_ + n];
  }
  sq2[n] = s; cross[n] = c;
}

// ---- wimg2 (+ appended wimg cols + zero pad) -> bf16, layout [G][KKP_]
__global__ __launch_bounds__(256) void w2conv_kernel(
    const float* __restrict__ wimg2, const float* __restrict__ wimg,
    unsigned short* __restrict__ W2){
  int g = blockIdx.x;
  const float* src = wimg2 + (size_t)g * KK_;
  unsigned short* dst = W2 + (size_t)g * KKP_;
  for (int kk = threadIdx.x; kk < KKP_; kk += 256){
    float v;
    if (kk < KK_)       v = src[kk];
    else if (kk < KKE_) v = wimg[g*K_ + (kk - KK_)];
    else                v = 0.f;
    dst[kk] = f2bf(v);
  }
}

// ---- encode+decode probabilities per b (256 thr); writes R row (bf16)
__global__ __launch_bounds__(256) void encdec_kernel(
    const float* __restrict__ img,  const float* __restrict__ wimg,
    const float* __restrict__ wrec, const float* __restrict__ wrec2,
    const float* __restrict__ wrecT, const float* __restrict__ wrec2T,
    const unsigned short* __restrict__ W2,
    const float* __restrict__ c1norm, const float* __restrict__ w3norm,
    const float* __restrict__ w6norm, const float* __restrict__ sq2,
    const float* __restrict__ cross, unsigned short* __restrict__ Rm){
  __shared__ float simg[G_];
  __shared__ float sp[K_];           // p (xp_d)
  __shared__ float sq[J_ + 3];       // xp2, then q (xp2_d)
  __shared__ float slat[E2_];
  __shared__ float sd1[K_];          // dot(img, wimg col k)
  __shared__ float sh[2*K_];         // half-partials
  __shared__ float redf[4];
  __shared__ int   redi[4];

  int t = threadIdx.x;
  int b = blockIdx.x;
  int tt = t & 127, h = t >> 7;

  // -- stage 1: xp1 = softmax_k( -(||img-c_k||^2)/512 )
  simg[t      ] = img[b*G_ + t      ];
  simg[t + 256] = img[b*G_ + t + 256];
  __syncthreads();
  float a0 = simg[t], a1 = simg[t+256];
  float imgnorm = blockSum256(a0*a0 + a1*a1, redf, t);

  {
    float d0=0,d1v=0,d2=0,d3v=0;
    int g0 = h * 256;
    const float* wcol = wimg + tt;
    for (int g = g0; g < g0 + 256; g += 4){
      d0  += simg[g  ] * wcol[(g  )*K_];
      d1v += simg[g+1] * wcol[(g+1)*K_];
      d2  += simg[g+2] * wcol[(g+2)*K_];
      d3v += simg[g+3] * wcol[(g+3)*K_];
    }
    sh[h*128 + tt] = (d0+d1v)+(d2+d3v);
  }
  __syncthreads();
  float d1 = sh[tt] + sh[128 + tt];
  if (h == 0) sd1[tt] = d1;
  float xh1 = -(imgnorm - 2.f*d1 + c1norm[tt]) * (1.f/512.f);
  float m1 = blockMax256(xh1, redf, t);
  float ex1 = expf(xh1 - m1);
  float s1 = blockSum256((h == 0) ? ex1 : 0.f, redf, t);
  float xp1 = ex1 / s1;

  // -- stage 2: lat = xp1 @ wrec (e = tt, split k by half)
  __syncthreads();               // sh reuse
  if (h == 0) sp[tt] = xp1;      // temporarily store xp1 for the matvec
  __syncthreads();
  {
    float l0=0,l1=0;
    int k0 = h * 64;
    for (int k = k0; k < k0 + 64; k += 2){
      l0 += sp[k  ] * wrec[(k  )*E2_ + tt];
      l1 += sp[k+1] * wrec[(k+1)*E2_ + tt];
    }
    sh[h*128 + tt] = l0 + l1;
  }
  __syncthreads();
  float lat = sh[tt] + sh[128 + tt];
  if (h == 0) slat[tt] = lat;
  float latnorm = blockSum256((h == 0) ? lat*lat : 0.f, redf, t);

  // -- stage 3: d3 = lat @ wrecT col k (k = tt, split e by half); softmax + argmax
  __syncthreads();
  {
    float l0=0,l1=0;
    int e0 = h * 64;
    for (int e = e0; e < e0 + 64; e += 2){
      l0 += slat[e  ] * wrecT[(e  )*K_ + tt];
      l1 += slat[e+1] * wrecT[(e+1)*K_ + tt];
    }
    sh[h*128 + tt] = l0 + l1;
  }
  __syncthreads();
  float d3 = sh[tt] + sh[128 + tt];
  float xh3 = -(latnorm - 2.f*d3 + w3norm[tt]) * (1.f/128.f);
  float m3 = blockMax256(xh3, redf, t);
  float ex3 = expf(xh3 - m3);
  float s3 = blockSum256((h == 0) ? ex3 : 0.f, redf, t);
  if (h == 0) sp[tt] = ex3 / s3;          // final p (xp_d)
  int idxb = blockArgmax256(xh3, tt, redf, redi, t);
  __syncthreads();
  float dsq = imgnorm - 2.f*sd1[idxb] + c1norm[idxb];

  // -- stage 5: di[j] = sum_g simg[g]*W2[g][idxb*J+j]  (j = t, active t<129)
  float xh2 = -3e38f;
  if (t < J_){
    const unsigned short* Wb = W2 + (size_t)idxb * J_ + t;
    float di0=0,di1=0,di2=0,di3=0;
    for (int g = 0; g < G_; g += 4){
      di0 += simg[g  ] * bf2f(Wb[(size_t)(g  )*KKP_]);
      di1 += simg[g+1] * bf2f(Wb[(size_t)(g+1)*KKP_]);
      di2 += simg[g+2] * bf2f(Wb[(size_t)(g+2)*KKP_]);
      di3 += simg[g+3] * bf2f(Wb[(size_t)(g+3)*KKP_]);
    }
    float di = (di0+di1)+(di2+di3);
    int nb = idxb*J_ + t;
    xh2 = -(dsq - 2.f*(di - cross[nb]) + sq2[nb]) * (1.f/512.f);
  }
  float m2 = blockMax256(xh2, redf, t);
  float ea = (t < J_) ? expf(xh2 - m2) : 0.f;
  float s2 = blockSum256(ea, redf, t);
  if (t < J_) sq[t] = ea / s2;
  __syncthreads();

  // -- stage 6: lat2 = xp2 @ wrec2 (e = tt, split j: h0 -> [0,65), h1 -> [65,129))
  {
    float l = 0.f;
    int j0 = h * 65, j1 = h ? J_ : 65;
    for (int j = j0; j < j1; j++)
      l += sq[j] * wrec2[j*E2_ + tt];
    sh[h*128 + tt] = l;
  }
  __syncthreads();
  float lat2 = sh[tt] + sh[128 + tt];
  if (h == 0) slat[tt] = lat2;
  float l2n = blockSum256((h == 0) ? lat2*lat2 : 0.f, redf, t);
  __syncthreads();

  // -- stage 7: d6[j] = lat2 @ wrec2T col j (j = t, active t<129)
  float xh6 = -3e38f;
  if (t < J_){
    float l0=0,l1=0;
    for (int e = 0; e < E2_; e += 2){
      l0 += slat[e  ] * wrec2T[(e  )*J_ + t];
      l1 += slat[e+1] * wrec2T[(e+1)*J_ + t];
    }
    xh6 = -(l2n - 2.f*(l0+l1) + w6norm[t]) * (1.f/128.f);
  }
  float m6 = blockMax256(xh6, redf, t);
  float e6 = (t < J_) ? expf(xh6 - m6) : 0.f;
  float s6 = blockSum256(e6, redf, t);
  if (t < J_) sq[t] = e6 / s6;
  __syncthreads();

  // -- R fill: [0,KK_): p_k*q_j ; [KK_,KKE_): p ; rest 0
  unsigned short* Rrow = Rm + (size_t)b * KKP_;
  for (int kk = t; kk < KKP_; kk += 256){
    float v;
    if (kk < KK_){
      int k = kk / J_;
      int j = kk - k*J_;
      v = sp[k] * sq[j];
    } else if (kk < KKE_){
      v = sp[kk - KK_];
    } else v = 0.f;
    Rrow[kk] = f2bf(v);
  }
}

// ---- big einsum as bf16 NT GEMM with split-K:
// part[z][b][g] = sum_{kk in chunk z} R[b,kk]*W2[g,kk]
__global__ __launch_bounds__(256) void gemm_kernel(
    const unsigned short* __restrict__ Rm, const unsigned short* __restrict__ W2,
    float* __restrict__ part){
  __shared__ __align__(16) unsigned int lds[2*128*20];   // 80B-stride rows, A then B
  unsigned int* lA = lds;
  unsigned int* lB = lds + 128*20;
  int tid = threadIdx.x;
  int l = tid & 63;
  int w = tid >> 6;
  int wr = (w >> 1) * 64, wc = (w & 1) * 64;
  int b0 = blockIdx.y * 128, g0 = blockIdx.x * 128;
  size_t kkbase = (size_t)blockIdx.z * KCHUNK;

  // staging: 256 threads cover rows [0,64) x 4 chunks of 16B; second load row+64.
  int srow = tid >> 2, scol = tid & 3;
  const unsigned short* pa = Rm + (size_t)(b0 + srow)*KKP_ + kkbase + scol*8;
  const unsigned short* pb = W2 + (size_t)(g0 + srow)*KKP_ + kkbase + scol*8;
  const size_t half = (size_t)64 * KKP_;
  unsigned int woff = srow*20 + scol*4;

  int lrow = l & 15, lko = (l >> 4) << 2;

  f32x4 zero4 = {0.f, 0.f, 0.f, 0.f};
  f32x4 acc[4][4];
  #pragma unroll
  for (int mi = 0; mi < 4; mi++)
    #pragma unroll
    for (int ni = 0; ni < 4; ni++) acc[mi][ni] = zero4;

  for (int s = 0; s < KSTEPS; s++){
    uint4 va0 = *(const uint4*)pa;
    uint4 va1 = *(const uint4*)(pa + half);
    uint4 vb0 = *(const uint4*)pb;
    uint4 vb1 = *(const uint4*)(pb + half);
    pa += BK_; pb += BK_;
    __syncthreads();                       // previous tile fully consumed
    *(uint4*)(lA + woff)          = va0;
    *(uint4*)(lA + woff + 64*20)  = va1;
    *(uint4*)(lB + woff)          = vb0;
    *(uint4*)(lB + woff + 64*20)  = vb1;
    __syncthreads();
    short8 af[4], bfv[4];
    #pragma unroll
    for (int mi = 0; mi < 4; mi++)
      af[mi] = *(const short8*)(lA + (wr + mi*16 + lrow)*20 + lko);
    #pragma unroll
    for (int ni = 0; ni < 4; ni++)
      bfv[ni] = *(const short8*)(lB + (wc + ni*16 + lrow)*20 + lko);
    #pragma unroll
    for (int mi = 0; mi < 4; mi++)
      #pragma unroll
      for (int ni = 0; ni < 4; ni++)
        acc[mi][ni] = __builtin_amdgcn_mfma_f32_16x16x32_bf16(af[mi], bfv[ni], acc[mi][ni], 0, 0, 0);
  }

  float* P = part + ((size_t)blockIdx.z * B_ + b0) * G_ + g0;
  int rh = (l >> 4) << 2, cl = l & 15;
  #pragma unroll
  for (int mi = 0; mi < 4; mi++)
    #pragma unroll
    for (int ni = 0; ni < 4; ni++)
      #pragma unroll
      for (int r = 0; r < 4; r++){
        int row = wr + mi*16 + rh + r;
        int col = wc + ni*16 + cl;
        P[(size_t)row*G_ + col] = acc[mi][ni][r];
      }
}

// ---- loss[b] = mean_g ( (sum_z part[z][b][g]) - img[b][g] )^2
__global__ __launch_bounds__(128) void loss_kernel(
    const float* __restrict__ img, const float* __restrict__ part,
    float* __restrict__ out){
  __shared__ float redf[2];
  int t = threadIdx.x, b = blockIdx.x;
  float acc = 0.f;
  for (int g = t; g < G_; g += 128){
    float x = 0.f;
    #pragma unroll
    for (int z = 0; z < SPLITS; z++)
      x += part[((size_t)z*B_ + b)*G_ + g];
    float d = x - img[b*G_ + g];
    acc += d*d;
  }
  #pragma unroll
  for (int off = 32; off > 0; off >>= 1) acc += __shfl_down(acc, off);
  __syncthreads();
  if ((t & 63) == 0) redf[t >> 6] = acc;
  __syncthreads();
  if (t == 0) out[b] = (redf[0] + redf[1]) * (1.f/512.f);
}

extern "C" void kernel_launch(void* const* d_in, const int* in_sizes, int n_in,
                              void* d_out, int out_size, void* d_ws, size_t ws_size,
                              hipStream_t stream){
  (void)in_sizes; (void)n_in; (void)out_size; (void)ws_size;
  const float* img   = (const float*)d_in[0];
  const float* wimg  = (const float*)d_in[1];
  const float* wrec  = (const float*)d_in[2];
  const float* wrec2 = (const float*)d_in[3];
  const float* wimg2 = (const float*)d_in[4];
  float* out = (float*)d_out;

  char* ws = (char*)d_ws;
  size_t off = 0;
  auto alloc = [&](size_t bytes) -> void* {
    void* p = ws + off;
    off += (bytes + 255) & ~(size_t)255;
    return p;
  };
  unsigned short* W2   = (unsigned short*)alloc((size_t)G_ * KKP_ * 2);
  unsigned short* Rm   = (unsigned short*)alloc((size_t)B_ * KKP_ * 2);
  float* part   = (float*)alloc((size_t)SPLITS * B_ * G_ * 4);
  float* sqp    = (float*)alloc((size_t)GS_ * KK_ * 4);
  float* crp    = (float*)alloc((size_t)GS_ * KK_ * 4);
  float* sq2    = (float*)alloc((size_t)KK_ * 4);
  float* cross  = (float*)alloc((size_t)KK_ * 4);
  float* c1norm = (float*)alloc(K_ * 4);
  float* w3norm = (float*)alloc(K_ * 4);
  float* w6norm = (float*)alloc(J_ * 4);
  float* wrecT  = (float*)alloc((size_t)K_ * E2_ * 4);
  float* wrec2T = (float*)alloc((size_t)J_ * E2_ * 4);

  norms_kernel<<<dim3(5), dim3(1024), 0, stream>>>(wimg, wrec, wrec2, c1norm, w3norm, w6norm, wrecT, wrec2T);
  tables_part_kernel<<<dim3(129, GS_), dim3(128), 0, stream>>>(wimg2, wimg, sqp, crp);
  tables_reduce_kernel<<<dim3(129), dim3(128), 0, stream>>>(sqp, crp, sq2, cross);
  w2conv_kernel<<<dim3(512), dim3(256), 0, stream>>>(wimg2, wimg, W2);
  encdec_kernel<<<dim3(1024), dim3(256), 0, stream>>>(img, wimg, wrec, wrec2, wrecT, wrec2T, W2,
      c1norm, w3norm, w6norm, sq2, cross, Rm);
  gemm_kernel<<<dim3(4, 8, SPLITS), dim3(256), 0, stream>>>(Rm, W2, part);
  loss_kernel<<<dim3(1024), dim3(128), 0, stream>>>(img, part, out);
}